// Round 5
// baseline (357.882 us; speedup 1.0000x reference)
//
#include <hip/hip_runtime.h>
#include <stdint.h>

// B=512, T=256, N_EMBED=384, HEAD_SIZE=64
// 3 kernels, all high-occupancy / small-LDS:
//  prep_w: W -> bf16 MFMA-B-fragment order Wt3[(kc*12+ntile)*512 + lane*8 + j]
//  qkv:    2048 blocks x 256thr; 64 x-rows/block; dbuf per-kc staging; writes
//          K/Q/V to global in MFMA fragment order (via LDS reorder).
//  attn:   2048 blocks x 256thr; block=(b,qt), wave w -> q-subtile qt+4w;
//          Q/K/V frags read from global (L2/L3-resident); P via wave LDS strip.
// Fragment-order layouts (shorts):
//  Qd: ((b*16+t)*2+f)*512 + lane*8 + j   (A-frag: m=q=t*16+(lane&15), k=h=f*32+(lane>>4)*8+j)
//  Kd: ((b*16+s)*2+f)*512 + lane*8 + j   (B-frag: n=s-col, k=h)
//  Vd: ((b*8+sb)*4+ht)*512 + lane*8 + j  (B-frag: n=h=ht*16+(lane&15), k=s=sb*32+(lane>>4)*8+j)

typedef short s16x8 __attribute__((ext_vector_type(8)));
typedef float f32x4 __attribute__((ext_vector_type(4)));

#define LOG2E_OVER_8 0.18033688011112042f

__device__ inline short f2bf(float f) {
  union { float f; uint32_t u; } v; v.f = f;
  uint32_t r = (v.u + 0x7fffu + ((v.u >> 16) & 1u)) >> 16;  // RNE
  return (short)r;
}

__global__ __launch_bounds__(256) void prep_w(const float* __restrict__ Wk,
                                              const float* __restrict__ Wq,
                                              const float* __restrict__ Wv,
                                              short* __restrict__ Wt3) {
  int idx = blockIdx.x * 256 + threadIdx.x;  // 0..73727
  int j = idx & 7;
  int lane = (idx >> 3) & 63;
  int rest = idx >> 9;          // 0..143
  int ntile = rest % 12;
  int kc = rest / 12;
  int n = ntile * 16 + (lane & 15);
  int kk = (lane >> 4) * 8 + j;
  int col = n & 63;
  int w = n >> 6;
  const float* W = (w == 0) ? Wk : (w == 1) ? Wq : Wv;
  float v = W[(kc * 32 + kk) * 64 + col];
  if (w == 1) v *= LOG2E_OVER_8;
  Wt3[idx] = f2bf(v);
}

// ---- QKV projection: block = (b, rb) -> rows rb*64..+63, all 192 cols.
__global__ __launch_bounds__(256, 4) void qkv(const float* __restrict__ x,
                                              const short* __restrict__ Wt3,
                                              short* __restrict__ Kd,
                                              short* __restrict__ Qd,
                                              short* __restrict__ Vd) {
  __shared__ __align__(16) short Xbuf[2][2048];  // dbuf: 64 rows x 32 kk, A-frag order
  __shared__ __align__(16) short Rb[12288];      // reorder: K 4K | Q 4K | V 4K shorts
  const int tid = threadIdx.x;
  const int wave = tid >> 6;
  const int lane = tid & 63;
  const int l15 = lane & 15;
  const int quad = lane >> 4;
  const int b = blockIdx.x >> 2;
  const int rb = blockIdx.x & 3;
  const float* xb = x + ((long)b * 256 + rb * 64) * 384;

  const int row = tid >> 2;         // 0..63
  const int c8 = (tid & 3) * 8;     // kk base 0,8,16,24
  const float* xp = xb + row * 384 + c8;
  const int xwoff = (row >> 4) * 512 + ((row & 15) + (c8 >> 3) * 16) * 8;
  const short* wp = Wt3 + (wave * 3) * 512 + lane * 8;  // ntg = wave*3 + lnt

  f32x4 acc[4][3];
#pragma unroll
  for (int mt = 0; mt < 4; ++mt)
#pragma unroll
    for (int lnt = 0; lnt < 3; ++lnt) acc[mt][lnt] = (f32x4)0.0f;

  f32x4 xa[2][2];
  s16x8 wv[2][3];
  xa[0][0] = *(const f32x4*)xp;
  xa[0][1] = *(const f32x4*)(xp + 4);
#pragma unroll
  for (int lnt = 0; lnt < 3; ++lnt) wv[0][lnt] = *(const s16x8*)(wp + lnt * 512);

#pragma unroll
  for (int kc = 0; kc < 12; ++kc) {
    const int cur = kc & 1, nxt = cur ^ 1;
    s16x8 hv;
    hv[0] = f2bf(xa[cur][0][0]); hv[1] = f2bf(xa[cur][0][1]);
    hv[2] = f2bf(xa[cur][0][2]); hv[3] = f2bf(xa[cur][0][3]);
    hv[4] = f2bf(xa[cur][1][0]); hv[5] = f2bf(xa[cur][1][1]);
    hv[6] = f2bf(xa[cur][1][2]); hv[7] = f2bf(xa[cur][1][3]);
    *(s16x8*)(&Xbuf[cur][0] + xwoff) = hv;
    __syncthreads();
    if (kc < 11) {  // prefetch next slice (x from HBM, W frags from L2)
      xa[nxt][0] = *(const f32x4*)(xp + (kc + 1) * 32);
      xa[nxt][1] = *(const f32x4*)(xp + (kc + 1) * 32 + 4);
#pragma unroll
      for (int lnt = 0; lnt < 3; ++lnt)
        wv[nxt][lnt] = *(const s16x8*)(wp + (kc + 1) * 6144 + lnt * 512);
    }
    s16x8 af[4];
#pragma unroll
    for (int mt = 0; mt < 4; ++mt)
      af[mt] = *(const s16x8*)(&Xbuf[cur][0] + mt * 512 + lane * 8);
#pragma unroll
    for (int lnt = 0; lnt < 3; ++lnt)
#pragma unroll
      for (int mt = 0; mt < 4; ++mt)
        acc[mt][lnt] = __builtin_amdgcn_mfma_f32_16x16x32_bf16(af[mt], wv[cur][lnt], acc[mt][lnt], 0, 0, 0);
  }

  // reorder C-frags (row=mt*16+quad*4+r, col=ntg*16+l15) -> fragment order in Rb
#pragma unroll
  for (int mt = 0; mt < 4; ++mt) {
#pragma unroll
    for (int lnt = 0; lnt < 3; ++lnt) {
      const int ntg = wave * 3 + lnt;  // wave-uniform
#pragma unroll
      for (int r = 0; r < 4; ++r) {
        const short v = f2bf(acc[mt][lnt][r]);
        if (ntg < 8) {  // K or Q: same formula, different region
          const int h = (ntg & 3) * 16 + l15;
          const int base = (ntg < 4) ? 0 : 4096;
          Rb[base + (mt * 2 + (h >> 5)) * 512 + ((quad * 4 + r) + ((h & 31) >> 3) * 16) * 8 + (h & 7)] = v;
        } else {
          const int ht = ntg - 8;
          const int rr = mt * 16 + quad * 4 + r;
          Rb[8192 + ((rr >> 5) * 4 + ht) * 512 + (l15 + ((rr & 31) >> 3) * 16) * 8 + (rr & 7)] = v;
        }
      }
    }
  }
  __syncthreads();

  // dump: contiguous dwordx4 stores to fragment-ordered global
  const long Kbase = ((long)b * 16 + rb * 4) * 1024;
  const long Vbase = ((long)b * 8 + rb * 2) * 2048;
#pragma unroll
  for (int i = 0; i < 6; ++i) {
    const int s = (tid + i * 256) * 8;
    s16x8 vdat = *(const s16x8*)&Rb[s];
    if (i < 2)      *(s16x8*)(Kd + Kbase + s) = vdat;
    else if (i < 4) *(s16x8*)(Qd + Kbase + (s - 4096)) = vdat;
    else            *(s16x8*)(Vd + Vbase + (s - 8192)) = vdat;
  }
}

// ---- Attention: block=(b, qt); wave w -> subtile t=qt+4w; 64-wide s-chunks.
__global__ __launch_bounds__(256, 5) void attn(const short* __restrict__ Kd,
                                               const short* __restrict__ Qd,
                                               const short* __restrict__ Vd,
                                               float* __restrict__ out) {
  __shared__ __align__(16) short P[4][1024];  // per-wave A-frag strip, 2 x 32-s blocks
  const int tid = threadIdx.x;
  const int wave = tid >> 6;
  const int lane = tid & 63;
  const int l15 = lane & 15;
  const int quad = lane >> 4;
  const int b = blockIdx.x >> 2;
  const int qt = blockIdx.x & 3;
  const int t = qt + wave * 4;  // q-subtile 0..15
  const int q0 = t * 16;
  short* Pw = &P[wave][0];

  s16x8 qf0 = *(const s16x8*)(Qd + (((long)b * 16 + t) * 2 + 0) * 512 + lane * 8);
  s16x8 qf1 = *(const s16x8*)(Qd + (((long)b * 16 + t) * 2 + 1) * 512 + lane * 8);

  f32x4 Oacc[4];
#pragma unroll
  for (int n = 0; n < 4; ++n) Oacc[n] = (f32x4)0.0f;
  float mrow[4] = {-1e30f, -1e30f, -1e30f, -1e30f};
  float lrow[4] = {0.f, 0.f, 0.f, 0.f};

  const int nch = (t >> 2) + 1;
  for (int c = 0; c < nch; ++c) {
    const int st0 = c * 4;
    const int nuse = min(4, t - st0 + 1);  // live 16-s tiles this chunk (wave-uniform)

    // issue all live K-frag loads up front (L2/L3 resident)
    s16x8 kf0[4], kf1[4];
#pragma unroll
    for (int n = 0; n < 4; ++n) {
      if (n < nuse) {
        const long kb = (((long)b * 16 + st0 + n) * 2) * 512 + lane * 8;
        kf0[n] = *(const s16x8*)(Kd + kb);
        kf1[n] = *(const s16x8*)(Kd + kb + 512);
      }
    }
    float S[4][4];
#pragma unroll
    for (int n = 0; n < 4; ++n) {
      if (n < nuse) {
        f32x4 z = (f32x4)0.0f;
        z = __builtin_amdgcn_mfma_f32_16x16x32_bf16(qf0, kf0[n], z, 0, 0, 0);
        z = __builtin_amdgcn_mfma_f32_16x16x32_bf16(qf1, kf1[n], z, 0, 0, 0);
        if (st0 + n == t) {  // diagonal tile: mask s > q
          const int s_abs = (st0 + n) * 16 + l15;
#pragma unroll
          for (int r = 0; r < 4; ++r)
            S[n][r] = (s_abs > q0 + quad * 4 + r) ? -1e30f : z[r];
        } else {
#pragma unroll
          for (int r = 0; r < 4; ++r) S[n][r] = z[r];
        }
      } else {
#pragma unroll
        for (int r = 0; r < 4; ++r) S[n][r] = -1e30f;
      }
    }

    // online softmax (base-2); row r lives in the 16 lanes of this quad
    float alpha[4];
#pragma unroll
    for (int r = 0; r < 4; ++r) {
      float mx = fmaxf(fmaxf(S[0][r], S[1][r]), fmaxf(S[2][r], S[3][r]));
      mx = fmaxf(mx, __shfl_xor(mx, 1));
      mx = fmaxf(mx, __shfl_xor(mx, 2));
      mx = fmaxf(mx, __shfl_xor(mx, 4));
      mx = fmaxf(mx, __shfl_xor(mx, 8));
      float mnew = fmaxf(mrow[r], mx);
      alpha[r] = __builtin_amdgcn_exp2f(mrow[r] - mnew);
      mrow[r] = mnew;
    }
    float rs[4] = {0.f, 0.f, 0.f, 0.f};
#pragma unroll
    for (int n = 0; n < 4; ++n) {
#pragma unroll
      for (int r = 0; r < 4; ++r) {
        float p = __builtin_amdgcn_exp2f(S[n][r] - mrow[r]);  // masked/dead -> 0
        rs[r] += p;
        Pw[(n >> 1) * 512 + ((quad * 4 + r) + ((n & 1) * 2 + (l15 >> 3)) * 16) * 8 + (l15 & 7)] = f2bf(p);
      }
    }
#pragma unroll
    for (int r = 0; r < 4; ++r) {
      float s = rs[r];
      s += __shfl_xor(s, 1);
      s += __shfl_xor(s, 2);
      s += __shfl_xor(s, 4);
      s += __shfl_xor(s, 8);
      lrow[r] = lrow[r] * alpha[r] + s;
#pragma unroll
      for (int n = 0; n < 4; ++n) Oacc[n][r] *= alpha[r];
    }
    // P strip is wave-private: drain DS writes before re-reading (no barrier)
    asm volatile("s_waitcnt lgkmcnt(0)" ::: "memory");

    const int kblks = (nuse + 1) >> 1;
    for (int sb = 0; sb < kblks; ++sb) {
      s16x8 pf = *(const s16x8*)(Pw + sb * 512 + lane * 8);
#pragma unroll
      for (int ht = 0; ht < 4; ++ht) {
        s16x8 vf = *(const s16x8*)(Vd + (((long)b * 8 + c * 2 + sb) * 4 + ht) * 512 + lane * 8);
        Oacc[ht] = __builtin_amdgcn_mfma_f32_16x16x32_bf16(pf, vf, Oacc[ht], 0, 0, 0);
      }
    }
  }

  float inv[4];
#pragma unroll
  for (int r = 0; r < 4; ++r) inv[r] = 1.0f / lrow[r];
  float* ob = out + ((long)b * 256 + q0 + quad * 4) * 64;
#pragma unroll
  for (int n = 0; n < 4; ++n)
#pragma unroll
    for (int r = 0; r < 4; ++r)
      ob[r * 64 + n * 16 + l15] = Oacc[n][r] * inv[r];
}

extern "C" void kernel_launch(void* const* d_in, const int* in_sizes, int n_in,
                              void* d_out, int out_size, void* d_ws, size_t ws_size,
                              hipStream_t stream) {
  const float* x = (const float*)d_in[0];
  const float* Wk = (const float*)d_in[1];
  const float* Wq = (const float*)d_in[2];
  const float* Wv = (const float*)d_in[3];
  float* out = (float*)d_out;
  char* ws = (char*)d_ws;
  short* Wt3 = (short*)ws;                           // 147456 B
  short* Kd = (short*)(ws + 262144);                 // 16 MiB each
  short* Qd = (short*)(ws + 262144 + 16777216);
  short* Vd = (short*)(ws + 262144 + 2 * 16777216);

  prep_w<<<288, 256, 0, stream>>>(Wk, Wq, Wv, Wt3);
  qkv<<<2048, 256, 0, stream>>>(x, Wt3, Kd, Qd, Vd);
  attn<<<2048, 256, 0, stream>>>(Kd, Qd, Vd, out);
}